// Round 1
// baseline (897.613 us; speedup 1.0000x reference)
//
#include <hip/hip_runtime.h>

#define TAGS 128
#define SEQ 1024
#define BATCH 128
#define SHIFT 5.3515f   // arbitrary block-uniform centering constant (numerics only)

// One block per batch element. Thread u owns tag-column u.
// Forward recurrence kept in scaled-linear space:
//   pre_i[u] = C + log(p_i[u]),  p_i[u] = (Σ_t p_{i-1}[t]·e^{A[t,u]}) · e^{yp_i[u]-SHIFT} / p_{i-1}[0]
//   C += SHIFT + log(p_{i-1}[0])
// e^{A[:,u]} lives in 128 VGPRs; p vector exchanged via double-buffered LDS
// (broadcast float4 reads, conflict-free), ONE barrier per step.
__global__ __launch_bounds__(128, 1)
void crf_fwd(const float* __restrict__ yp, const int* __restrict__ yt,
             const float* __restrict__ mask, const float* __restrict__ A,
             float* __restrict__ out)
{
    const int b = blockIdx.x;
    const int u = threadIdx.x;

    __shared__ __align__(16) float pbuf[2][TAGS];
    __shared__ float wred[4];

    const float* __restrict__ ypb = yp + (size_t)b * SEQ * TAGS;
    const float* __restrict__ mb  = mask + (size_t)b * SEQ;
    const int*   __restrict__ ytb = yt + (size_t)b * SEQ;

    // ---- transition column u, exponentiated, in registers ----
    float ea[TAGS];
#pragma unroll
    for (int t = 0; t < TAGS; ++t)
        ea[t] = __expf(A[t * TAGS + u]);

    // ---- gold-path score partial (8 positions per thread) ----
    float sc = 0.f;
#pragma unroll
    for (int k = 0; k < SEQ / TAGS; ++k) {
        int s = u + k * TAGS;
        int l = ytb[s];
        float m = mb[s];
        sc += ypb[s * TAGS + l] * m;
        if (s + 1 < SEQ) {
            int l2 = ytb[s + 1];
            sc += A[l * TAGS + l2] * m * mb[s + 1];
        }
    }

    // ---- init forward state: p0 = exp(yp[b,0,:]), C = 0 ----
    float pv = __expf(ypb[u]);
    pbuf[0][u] = pv;
    float p_self = pv;        // own p value, avoids LDS read for masked steps
    double C = 0.0;

    // 2-deep prefetch pipeline for yp / mask (covers ~900cyc HBM latency)
    float yp1 = ypb[TAGS + u];
    float m1  = mb[1];
    float yp2 = ypb[2 * TAGS + u];
    float m2  = mb[2];

    __syncthreads();

    int cur = 0;
#pragma unroll 1
    for (int i = 1; i < SEQ; ++i) {
        // prefetch inputs for step i+2
        float ypf = 0.f, mf = 0.f;
        if (i + 2 < SEQ) {
            ypf = ypb[(i + 2) * TAGS + u];
            mf  = mb[i + 2];
        }
        float g = __expf(yp1 - SHIFT);   // off critical chain (input-only)
        float m = m1;

        // ---- matvec: s[u] = Σ_t p[t] * e^{A[t,u]} ----
        const float4* pq = (const float4*)pbuf[cur];
        float a0 = 0.f, a1 = 0.f, a2 = 0.f, a3 = 0.f;
        float p00 = 0.f;
#pragma unroll
        for (int k = 0; k < TAGS / 4; ++k) {
            float4 q = pq[k];            // broadcast ds_read_b128, conflict-free
            if (k == 0) p00 = q.x;
            a0 = fmaf(q.x, ea[4 * k + 0], a0);
            a1 = fmaf(q.y, ea[4 * k + 1], a1);
            a2 = fmaf(q.z, ea[4 * k + 2], a2);
            a3 = fmaf(q.w, ea[4 * k + 3], a3);
        }
        float s = (a0 + a1) + (a2 + a3);

        bool act = (m > 0.5f);           // mask is {0,1}; all-ones in this input
        float pn = act ? (s * g) / p00 : p_self;
        if (act) C += (double)(SHIFT + __logf(p00));
        p_self = pn;
        pbuf[cur ^ 1][u] = pn;
        __syncthreads();                 // single barrier/step (double buffer)
        cur ^= 1;

        yp1 = yp2; m1 = m2; yp2 = ypf; m2 = mf;
    }

    // ---- final reductions: T = Σ_u p_final[u], score = Σ sc ----
    float tot = p_self;
    float sct = sc;
#pragma unroll
    for (int off = 32; off > 0; off >>= 1) {
        tot += __shfl_down(tot, off, 64);
        sct += __shfl_down(sct, off, 64);
    }
    if ((u & 63) == 0) {
        wred[(u >> 6)]     = tot;
        wred[2 + (u >> 6)] = sct;
    }
    __syncthreads();
    if (u == 0) {
        float T     = wred[0] + wred[1];
        float score = wred[2] + wred[3];
        float logZ  = (float)(C + (double)__logf(T));
        float loss  = (logZ - score) * (1.0f / (float)BATCH);
        atomicAdd(out, loss);
    }
}

extern "C" void kernel_launch(void* const* d_in, const int* in_sizes, int n_in,
                              void* d_out, int out_size, void* d_ws, size_t ws_size,
                              hipStream_t stream) {
    const float* yp   = (const float*)d_in[0];   // (128,1024,128) f32
    const int*   yt   = (const int*)d_in[1];     // (128,1024) int
    const float* mask = (const float*)d_in[2];   // (128,1024) f32
    const float* A    = (const float*)d_in[3];   // (128,128) f32
    float* out = (float*)d_out;                  // scalar f32

    hipMemsetAsync(out, 0, sizeof(float), stream);
    crf_fwd<<<BATCH, TAGS, 0, stream>>>(yp, yt, mask, A, out);
}